// Round 7
// baseline (667.350 us; speedup 1.0000x reference)
//
#include <hip/hip_runtime.h>
#include <math.h>

#define CH 64

// ---- multi-value wave reduction ----------------------------------------
// Sums 8 per-lane values over all 64 lanes; returns all 8 totals in L[0..7]
// in every lane. Merge-tree: 18 shuffles instead of 48. After the 3 merge
// stages lane l owns value j=(l>>3)&7; broadcast from lane 8j.
__device__ __forceinline__ void multi_reduce8(const float lv[8], float L[8], int lane) {
  bool b5 = (lane & 32) != 0;
  float r1[4];
#pragma unroll
  for (int j = 0; j < 4; ++j) {
    float keep = b5 ? lv[j + 4] : lv[j];
    float send = b5 ? lv[j] : lv[j + 4];
    r1[j] = keep + __shfl_xor(send, 32, 64);
  }
  bool b4 = (lane & 16) != 0;
  float r2[2];
#pragma unroll
  for (int j = 0; j < 2; ++j) {
    float keep = b4 ? r1[j + 2] : r1[j];
    float send = b4 ? r1[j] : r1[j + 2];
    r2[j] = keep + __shfl_xor(send, 16, 64);
  }
  bool b3 = (lane & 8) != 0;
  float keep = b3 ? r2[1] : r2[0];
  float send = b3 ? r2[0] : r2[1];
  float v = keep + __shfl_xor(send, 8, 64);
  v += __shfl_xor(v, 4, 64);
  v += __shfl_xor(v, 2, 64);
  v += __shfl_xor(v, 1, 64);
#pragma unroll
  for (int j = 0; j < 8; ++j) L[j] = __shfl(v, j * 8, 64);
}

// ---- CSR build ----------------------------------------------------------
// Single packed u64 atomic per edge: high 24 bits = count, low 40 bits =
// fixed-point (2^-25) weight sum. The returned old count = this edge's
// rank within its dst row -> scatter needs no atomics at all.

#define WSUM_SCALE 33554432.0f  // 2^25
#define WSUM_MASK 0xFFFFFFFFFFULL

__global__ void k_count(const int* __restrict__ dst, const float* __restrict__ w, int E,
                        unsigned long long* __restrict__ agg, int* __restrict__ rank) {
  int i = blockIdx.x * blockDim.x + threadIdx.x;
  if (i < E) {
    int d = dst[i];
    unsigned long long pk =
        (1ULL << 40) | (unsigned long long)(w[i] * WSUM_SCALE);
    unsigned long long old = atomicAdd(&agg[d], pk);
    rank[i] = (int)(old >> 40);
  }
}

// per-node: loop_attr, deg, row_beg via wave-aggregated atomic allocation
__global__ void k_alloc(const unsigned long long* __restrict__ agg,
                        float* __restrict__ loop_attr, int* __restrict__ deg,
                        int* __restrict__ row_beg, int* __restrict__ total, int n) {
  int i = blockIdx.x * blockDim.x + threadIdx.x;
  int lane = threadIdx.x & 63;
  int d = 0;
  if (i < n) {
    unsigned long long v = agg[i];
    int c = (int)(v >> 40);
    float ws = (float)(v & WSUM_MASK) * (1.0f / WSUM_SCALE);
    loop_attr[i] = ws / fmaxf((float)c, 1.0f);
    d = c + 1;  // +1 self-loop
    deg[i] = d;
  }
  int x = d;
#pragma unroll
  for (int off = 1; off < 64; off <<= 1) {
    int t = __shfl_up(x, off, 64);
    if (lane >= off) x += t;
  }
  int base = 0;
  if (lane == 63) base = atomicAdd(total, x);
  base = __shfl(base, 63, 64);
  if (i < n) row_beg[i] = base + x - d;  // exclusive within wave
}

// atomic-free scatter using precomputed rank
__global__ void k_scatter(const int* __restrict__ src, const int* __restrict__ dst,
                          const float* __restrict__ w, const int* __restrict__ rank, int E,
                          const int* __restrict__ row_beg, int2* __restrict__ csr) {
  int i = blockIdx.x * blockDim.x + threadIdx.x;
  if (i < E) {
    int d = dst[i];
    csr[row_beg[d] + rank[i]] = make_int2(src[i], __float_as_int(w[i]));
  }
}

// self-loop goes in the last slot of each row (index deg-1 = original count)
__global__ void k_selfloop(int n, const int* __restrict__ row_beg, const int* __restrict__ deg,
                           int2* __restrict__ csr, const float* __restrict__ loop_attr) {
  int v = blockIdx.x * blockDim.x + threadIdx.x;
  if (v < n) {
    csr[row_beg[v] + deg[v] - 1] = make_int2(v, __float_as_int(loop_attr[v]));
  }
}

// ---- transform: xl = x@Wl + bl ; xr = x@Wr + br (wave/row, lane=out ch) --

__global__ void __launch_bounds__(256) k_transform(
    const float* __restrict__ x, const float* __restrict__ Wl, const float* __restrict__ bl,
    const float* __restrict__ Wr, const float* __restrict__ br,
    float* __restrict__ xl, float* __restrict__ xr, int n) {
  __shared__ float sW[2][CH * CH];  // 32 KB
  for (int i = threadIdx.x; i < (CH * CH) / 4; i += blockDim.x) {
    ((float4*)sW[0])[i] = ((const float4*)Wl)[i];
    ((float4*)sW[1])[i] = ((const float4*)Wr)[i];
  }
  __syncthreads();
  int lane = threadIdx.x & 63;
  int wid = threadIdx.x >> 6;
  float blc = bl[lane], brc = br[lane];
  int wavesPerGrid = (gridDim.x * blockDim.x) >> 6;
  for (int row = blockIdx.x * (blockDim.x >> 6) + wid; row < n; row += wavesPerGrid) {
    float xv = x[(size_t)row * CH + lane];
    float accl = blc, accr = brc;
#pragma unroll
    for (int k = 0; k < CH; ++k) {
      float xk = __shfl(xv, k, 64);
      accl = fmaf(xk, sW[0][k * CH + lane], accl);
      accr = fmaf(xk, sW[1][k * CH + lane], accr);
    }
    xl[(size_t)row * CH + lane] = accl;
    xr[(size_t)row * CH + lane] = accr;
  }
}

// ---- aggregate: one wave per node, online softmax over in-edges ----------
// 8-edge batches, 8 gathers in flight, merge-tree logit reduction, fast exp.

__global__ void __launch_bounds__(256) k_aggregate(
    const float* __restrict__ xl, const float* __restrict__ xr,
    const int* __restrict__ row_beg, const int* __restrict__ deg,
    const int2* __restrict__ csr,
    const float* __restrict__ We, const float* __restrict__ att, const float* __restrict__ bo,
    float* __restrict__ out, int n) {
  int lane = threadIdx.x & 63;
  int v = (blockIdx.x * blockDim.x + threadIdx.x) >> 6;
  if (v >= n) return;
  float Wec = We[lane], attc = att[lane], boc = bo[lane];
  float xrc = xr[(size_t)v * CH + lane];
  int beg = row_beg[v], dv = deg[v];
  float m = -INFINITY, s = 0.f, acc = 0.f;
  for (int chunk = 0; chunk < dv; chunk += 64) {
    int nc = min(64, dv - chunk);
    int2 ed = (lane < nc) ? csr[beg + chunk + lane] : make_int2(0, 0);
    for (int e = 0; e < nc; e += 8) {
      float xv[8], lv[8], L[8];
#pragma unroll
      for (int j = 0; j < 8; ++j) {
        int sj = __shfl(ed.x, e + j, 64);
        xv[j] = xl[(size_t)sj * CH + lane];  // 8 independent gathers in flight
      }
#pragma unroll
      for (int j = 0; j < 8; ++j) {
        float aj = __int_as_float(__shfl(ed.y, e + j, 64));
        float ee = fmaf(aj, Wec, xv[j] + xrc);
        lv[j] = (ee > 0.f ? ee : 0.2f * ee) * attc;
      }
      multi_reduce8(lv, L, lane);
#pragma unroll
      for (int j = 0; j < 8; ++j)
        if (e + j >= nc) L[j] = -INFINITY;  // masked tail
      float bm = fmaxf(fmaxf(fmaxf(L[0], L[1]), fmaxf(L[2], L[3])),
                       fmaxf(fmaxf(L[4], L[5]), fmaxf(L[6], L[7])));
      float mn = fmaxf(m, bm);
      float sc = __expf(m - mn);  // first batch: exp(-inf)=0
      float psum = 0.f, pdot = 0.f;
#pragma unroll
      for (int j = 0; j < 8; ++j) {
        float p = __expf(L[j] - mn);
        psum += p;
        pdot = fmaf(p, xv[j], pdot);
      }
      s = fmaf(s, sc, psum);
      acc = fmaf(acc, sc, pdot);
      m = mn;
    }
  }
  out[(size_t)v * CH + lane] = acc / s + boc;
}

// last layer: C_out = 1. xl8[v] = x[v,:]@Wl8 + bl8 (wave per node)
__global__ void __launch_bounds__(256) k_transform8(
    const float* __restrict__ x, const float* __restrict__ Wl, const float* __restrict__ bl,
    const float* __restrict__ Wr, const float* __restrict__ br,
    float* __restrict__ xl8, float* __restrict__ xr8, int n) {
  int lane = threadIdx.x & 63;
  int v = (blockIdx.x * blockDim.x + threadIdx.x) >> 6;
  if (v >= n) return;
  float xv = x[(size_t)v * CH + lane];
  float a = xv * Wl[lane];
  float b = xv * Wr[lane];
#pragma unroll
  for (int off = 32; off > 0; off >>= 1) {
    a += __shfl_xor(a, off, 64);
    b += __shfl_xor(b, off, 64);
  }
  if (lane == 0) {
    xl8[v] = a + bl[0];
    xr8[v] = b + br[0];
  }
}

// last layer aggregation (scalar channel), lane-per-edge, fused mean pool
__global__ void __launch_bounds__(256) k_agg8_mean(
    const float* __restrict__ xl8, const float* __restrict__ xr8,
    const int* __restrict__ row_beg, const int* __restrict__ deg,
    const int2* __restrict__ csr,
    const float* __restrict__ We, const float* __restrict__ att, const float* __restrict__ bo,
    float* __restrict__ out, int n) {
  int lane = threadIdx.x & 63;
  int wid = threadIdx.x >> 6;
  float We0 = We[0], att0 = att[0], bo0 = bo[0];
  float inv_n = 1.0f / (float)n;
  float local = 0.f;
  int nwaves = gridDim.x * 4;
  for (int v = blockIdx.x * 4 + wid; v < n; v += nwaves) {
    float xrc = xr8[v];
    int beg = row_beg[v], dv = deg[v];
    float m = -INFINITY, s = 0.f, acc = 0.f;
    for (int chunk = 0; chunk < dv; chunk += 64) {
      int idx = chunk + lane;
      bool valid = idx < dv;
      int2 ed = valid ? csr[beg + idx] : make_int2(0, 0);
      float xlc = valid ? xl8[ed.x] : 0.f;
      float ee = fmaf(__int_as_float(ed.y), We0, xlc + xrc);
      float logit = valid ? (ee > 0.f ? ee : 0.2f * ee) * att0 : -INFINITY;
      float bm = logit;
#pragma unroll
      for (int off = 32; off > 0; off >>= 1) bm = fmaxf(bm, __shfl_xor(bm, off, 64));
      float mn = fmaxf(m, bm);
      float p = __expf(logit - mn);
      float pd = p * xlc;
#pragma unroll
      for (int off = 32; off > 0; off >>= 1) {
        p += __shfl_xor(p, off, 64);
        pd += __shfl_xor(pd, off, 64);
      }
      float sc = __expf(m - mn);
      s = fmaf(s, sc, p);
      acc = fmaf(acc, sc, pd);
      m = mn;
    }
    local += (acc / s + bo0) * inv_n;
  }
  __shared__ float sw[4];
  if (lane == 0) sw[wid] = local;
  __syncthreads();
  if (threadIdx.x == 0) atomicAdd(out, sw[0] + sw[1] + sw[2] + sw[3]);
}

// ---- host ---------------------------------------------------------------

extern "C" void kernel_launch(void* const* d_in, const int* in_sizes, int n_in,
                              void* d_out, int out_size, void* d_ws, size_t ws_size,
                              hipStream_t stream) {
  const float* features = (const float*)d_in[0];
  const int* edge_src = (const int*)d_in[1];
  const int* edge_dst = (const int*)d_in[2];
  const float* edge_w = (const float*)d_in[3];
  const int N = in_sizes[0] / CH;
  const int E = in_sizes[1];

  char* p = (char*)d_ws;
  auto take = [&](size_t bytes) {
    char* r = p;
    p += (bytes + 255) & ~(size_t)255;
    return r;
  };
  float* xA = (float*)take((size_t)N * CH * 4);
  float* xB = (float*)take((size_t)N * CH * 4);
  float* xl = (float*)take((size_t)N * CH * 4);
  float* xr = (float*)take((size_t)N * CH * 4);
  int2* csr = (int2*)take((size_t)(E + N) * 8);
  char* zero_region = take((size_t)N * 8 + 256);
  unsigned long long* agg = (unsigned long long*)zero_region;
  int* total = (int*)(zero_region + (size_t)N * 8);
  int* rank = (int*)take((size_t)E * 4);
  float* loop_attr = (float*)take((size_t)N * 4);
  int* deg = (int*)take((size_t)N * 4);
  int* row_beg = (int*)take((size_t)N * 4);
  float* xl8 = (float*)take((size_t)N * 4);
  float* xr8 = (float*)take((size_t)N * 4);

  hipMemsetAsync(zero_region, 0, (size_t)N * 8 + 256, stream);
  hipMemsetAsync(d_out, 0, sizeof(float), stream);

  const int tb = 256;
  k_count<<<(E + tb - 1) / tb, tb, 0, stream>>>(edge_dst, edge_w, E, agg, rank);
  k_alloc<<<(N + tb - 1) / tb, tb, 0, stream>>>(agg, loop_attr, deg, row_beg, total, N);
  k_scatter<<<(E + tb - 1) / tb, tb, 0, stream>>>(edge_src, edge_dst, edge_w, rank, E,
                                                  row_beg, csr);
  k_selfloop<<<(N + tb - 1) / tb, tb, 0, stream>>>(N, row_beg, deg, csr, loop_attr);

  // param pointers
  const float* Wl1 = (const float*)d_in[4];
  const float* bl1 = (const float*)d_in[5];
  const float* Wr1 = (const float*)d_in[6];
  const float* br1 = (const float*)d_in[7];
  const float* We1 = (const float*)d_in[8];
  const float* att1 = (const float*)d_in[9];
  const float* bo1 = (const float*)d_in[10];
  const float* Wlm = (const float*)d_in[11];
  const float* blm = (const float*)d_in[12];
  const float* Wrm = (const float*)d_in[13];
  const float* brm = (const float*)d_in[14];
  const float* Wem = (const float*)d_in[15];
  const float* attm = (const float*)d_in[16];
  const float* bom = (const float*)d_in[17];

  const int agg_grid = ((size_t)N * 64 + tb - 1) / tb;
  const float* x_cur = features;
  float* x_nxt = xA;
  // layers 1..7: transform (x_cur -> xl,xr) then aggregate (-> x_nxt)
  for (int layer = 0; layer < 7; ++layer) {
    const float *Wl, *bl, *Wr, *br, *We, *att, *bo;
    if (layer == 0) {
      Wl = Wl1; bl = bl1; Wr = Wr1; br = br1; We = We1; att = att1; bo = bo1;
    } else {
      int i = layer - 1;
      Wl = Wlm + (size_t)i * CH * CH;
      bl = blm + (size_t)i * CH;
      Wr = Wrm + (size_t)i * CH * CH;
      br = brm + (size_t)i * CH;
      We = Wem + (size_t)i * CH;
      att = attm + (size_t)i * CH;
      bo = bom + (size_t)i * CH;
    }
    k_transform<<<256, 256, 0, stream>>>(x_cur, Wl, bl, Wr, br, xl, xr, N);
    k_aggregate<<<agg_grid, tb, 0, stream>>>(xl, xr, row_beg, deg, csr, We, att, bo, x_nxt, N);
    x_cur = x_nxt;
    x_nxt = (x_nxt == xA) ? xB : xA;
  }
  // layer 8: 64->1 transform, aggregate + mean pool
  k_transform8<<<agg_grid, tb, 0, stream>>>(
      x_cur, (const float*)d_in[18], (const float*)d_in[19], (const float*)d_in[20],
      (const float*)d_in[21], xl8, xr8, N);
  k_agg8_mean<<<1024, 256, 0, stream>>>(xl8, xr8, row_beg, deg, csr, (const float*)d_in[22],
                                        (const float*)d_in[23], (const float*)d_in[24],
                                        (float*)d_out, N);
}

// Round 8
// 629.269 us; speedup vs baseline: 1.0605x; 1.0605x over previous
//
#include <hip/hip_runtime.h>
#include <math.h>

#define CH 64

// ---- multi-value wave reduction ----------------------------------------
// Sums 8 per-lane values over all 64 lanes; returns all 8 totals in L[0..7]
// in every lane. Merge-tree: 18 shuffles instead of 48. After the 3 merge
// stages lane l owns value j=(l>>3)&7; broadcast from lane 8j.
// HW-verified (R5-R7 all passed with absmax 0.0).
__device__ __forceinline__ void multi_reduce8(const float lv[8], float L[8], int lane) {
  bool b5 = (lane & 32) != 0;
  float r1[4];
#pragma unroll
  for (int j = 0; j < 4; ++j) {
    float keep = b5 ? lv[j + 4] : lv[j];
    float send = b5 ? lv[j] : lv[j + 4];
    r1[j] = keep + __shfl_xor(send, 32, 64);
  }
  bool b4 = (lane & 16) != 0;
  float r2[2];
#pragma unroll
  for (int j = 0; j < 2; ++j) {
    float keep = b4 ? r1[j + 2] : r1[j];
    float send = b4 ? r1[j] : r1[j + 2];
    r2[j] = keep + __shfl_xor(send, 16, 64);
  }
  bool b3 = (lane & 8) != 0;
  float keep = b3 ? r2[1] : r2[0];
  float send = b3 ? r2[0] : r2[1];
  float v = keep + __shfl_xor(send, 8, 64);
  v += __shfl_xor(v, 4, 64);
  v += __shfl_xor(v, 2, 64);
  v += __shfl_xor(v, 1, 64);
#pragma unroll
  for (int j = 0; j < 8; ++j) L[j] = __shfl(v, j * 8, 64);
}

// ---- online-softmax batch update (edges e..e+7 of current chunk) --------
struct AggState {
  float m, s, acc;
};

__device__ __forceinline__ void agg_batch8(const float xv[8], const int2& ed, int e, int nc,
                                           float Wec, float attc, float xrc, int lane,
                                           AggState& st) {
  float lv[8], L[8];
#pragma unroll
  for (int j = 0; j < 8; ++j) {
    float aj = __int_as_float(__shfl(ed.y, e + j, 64));
    float ee = fmaf(aj, Wec, xv[j] + xrc);
    lv[j] = (ee > 0.f ? ee : 0.2f * ee) * attc;
  }
  multi_reduce8(lv, L, lane);
#pragma unroll
  for (int j = 0; j < 8; ++j)
    if (e + j >= nc) L[j] = -INFINITY;  // masked tail
  float bm = fmaxf(fmaxf(fmaxf(L[0], L[1]), fmaxf(L[2], L[3])),
                   fmaxf(fmaxf(L[4], L[5]), fmaxf(L[6], L[7])));
  float mn = fmaxf(st.m, bm);
  float sc = __expf(st.m - mn);  // first batch: exp(-inf)=0
  float psum = 0.f, pdot = 0.f;
#pragma unroll
  for (int j = 0; j < 8; ++j) {
    float p = __expf(L[j] - mn);
    psum += p;
    pdot = fmaf(p, xv[j], pdot);
  }
  st.s = fmaf(st.s, sc, psum);
  st.acc = fmaf(st.acc, sc, pdot);
  st.m = mn;
}

#define LOAD8(dst, ebase)                                          \
  {                                                                \
    _Pragma("unroll") for (int j = 0; j < 8; ++j) {                \
      int sj = __shfl(ed.x, (ebase) + j, 64);                      \
      dst[j] = xl[(size_t)sj * CH + lane];                         \
    }                                                              \
  }

// core of the per-node online-softmax aggregation with double-buffered
// gathers (batch e+8 in flight while batch e is in the softmax update)
__device__ __forceinline__ AggState agg_node(const float* __restrict__ xl,
                                             const int2* __restrict__ csr, int beg, int dv,
                                             float Wec, float attc, float xrc, int lane) {
  AggState st;
  st.m = -INFINITY;
  st.s = 0.f;
  st.acc = 0.f;
  for (int chunk = 0; chunk < dv; chunk += 64) {
    int nc = min(64, dv - chunk);
    int2 ed = (lane < nc) ? csr[beg + chunk + lane] : make_int2(0, 0);
    float xva[8], xvb[8];
    LOAD8(xva, 0);
    int e = 0;
    for (;;) {
      if (e + 8 < nc) LOAD8(xvb, e + 8);
      agg_batch8(xva, ed, e, nc, Wec, attc, xrc, lane, st);
      e += 8;
      if (e >= nc) break;
      if (e + 8 < nc) LOAD8(xva, e + 8);
      agg_batch8(xvb, ed, e, nc, Wec, attc, xrc, lane, st);
      e += 8;
      if (e >= nc) break;
    }
  }
  return st;
}

// ---- CSR build ----------------------------------------------------------
// Single packed u64 atomic per edge: high 24 bits = count, low 40 bits =
// fixed-point (2^-25) weight sum. The returned old count = this edge's
// rank within its dst row -> scatter needs no atomics at all.

#define WSUM_SCALE 33554432.0f  // 2^25
#define WSUM_MASK 0xFFFFFFFFFFULL

__global__ void k_count(const int* __restrict__ dst, const float* __restrict__ w, int E,
                        unsigned long long* __restrict__ agg, int* __restrict__ rank) {
  int i = blockIdx.x * blockDim.x + threadIdx.x;
  if (i < E) {
    int d = dst[i];
    unsigned long long pk = (1ULL << 40) | (unsigned long long)(w[i] * WSUM_SCALE);
    unsigned long long old = atomicAdd(&agg[d], pk);
    rank[i] = (int)(old >> 40);
  }
}

// per-node: loop_attr, deg, row_beg via wave-aggregated atomic allocation
__global__ void k_alloc(const unsigned long long* __restrict__ agg,
                        float* __restrict__ loop_attr, int* __restrict__ deg,
                        int* __restrict__ row_beg, int* __restrict__ total, int n) {
  int i = blockIdx.x * blockDim.x + threadIdx.x;
  int lane = threadIdx.x & 63;
  int d = 0;
  if (i < n) {
    unsigned long long v = agg[i];
    int c = (int)(v >> 40);
    float ws = (float)(v & WSUM_MASK) * (1.0f / WSUM_SCALE);
    loop_attr[i] = ws / fmaxf((float)c, 1.0f);
    d = c + 1;  // +1 self-loop
    deg[i] = d;
  }
  int x = d;
#pragma unroll
  for (int off = 1; off < 64; off <<= 1) {
    int t = __shfl_up(x, off, 64);
    if (lane >= off) x += t;
  }
  int base = 0;
  if (lane == 63) base = atomicAdd(total, x);
  base = __shfl(base, 63, 64);
  if (i < n) row_beg[i] = base + x - d;  // exclusive within wave
}

// atomic-free scatter using precomputed rank
__global__ void k_scatter(const int* __restrict__ src, const int* __restrict__ dst,
                          const float* __restrict__ w, const int* __restrict__ rank, int E,
                          const int* __restrict__ row_beg, int2* __restrict__ csr) {
  int i = blockIdx.x * blockDim.x + threadIdx.x;
  if (i < E) {
    int d = dst[i];
    csr[row_beg[d] + rank[i]] = make_int2(src[i], __float_as_int(w[i]));
  }
}

// self-loop goes in the last slot of each row (index deg-1 = original count)
__global__ void k_selfloop(int n, const int* __restrict__ row_beg, const int* __restrict__ deg,
                           int2* __restrict__ csr, const float* __restrict__ loop_attr) {
  int v = blockIdx.x * blockDim.x + threadIdx.x;
  if (v < n) {
    csr[row_beg[v] + deg[v] - 1] = make_int2(v, __float_as_int(loop_attr[v]));
  }
}

// ---- transform: xl = x@Wl + bl ; xr = x@Wr + br (wave/row, lane=out ch) --

__global__ void __launch_bounds__(256) k_transform(
    const float* __restrict__ x, const float* __restrict__ Wl, const float* __restrict__ bl,
    const float* __restrict__ Wr, const float* __restrict__ br,
    float* __restrict__ xl, float* __restrict__ xr, int n) {
  __shared__ float sW[2][CH * CH];  // 32 KB
  for (int i = threadIdx.x; i < (CH * CH) / 4; i += blockDim.x) {
    ((float4*)sW[0])[i] = ((const float4*)Wl)[i];
    ((float4*)sW[1])[i] = ((const float4*)Wr)[i];
  }
  __syncthreads();
  int lane = threadIdx.x & 63;
  int wid = threadIdx.x >> 6;
  float blc = bl[lane], brc = br[lane];
  int wavesPerGrid = (gridDim.x * blockDim.x) >> 6;
  for (int row = blockIdx.x * (blockDim.x >> 6) + wid; row < n; row += wavesPerGrid) {
    float xv = x[(size_t)row * CH + lane];
    float accl = blc, accr = brc;
#pragma unroll
    for (int k = 0; k < CH; ++k) {
      float xk = __shfl(xv, k, 64);
      accl = fmaf(xk, sW[0][k * CH + lane], accl);
      accr = fmaf(xk, sW[1][k * CH + lane], accr);
    }
    xl[(size_t)row * CH + lane] = accl;
    xr[(size_t)row * CH + lane] = accr;
  }
}

// ---- aggregate: one wave per node (layers 1..6 output) -------------------

__global__ void __launch_bounds__(256) k_aggregate(
    const float* __restrict__ xl, const float* __restrict__ xr,
    const int* __restrict__ row_beg, const int* __restrict__ deg,
    const int2* __restrict__ csr,
    const float* __restrict__ We, const float* __restrict__ att, const float* __restrict__ bo,
    float* __restrict__ out, int n) {
  int lane = threadIdx.x & 63;
  int v = (blockIdx.x * blockDim.x + threadIdx.x) >> 6;
  if (v >= n) return;
  float Wec = We[lane], attc = att[lane], boc = bo[lane];
  float xrc = xr[(size_t)v * CH + lane];
  AggState st = agg_node(xl, csr, row_beg[v], deg[v], Wec, attc, xrc, lane);
  out[(size_t)v * CH + lane] = st.acc / st.s + boc;
}

// layer-7 aggregate with fused layer-8 transform (64->1): writes xl8/xr8
__global__ void __launch_bounds__(256) k_aggregate_t8(
    const float* __restrict__ xl, const float* __restrict__ xr,
    const int* __restrict__ row_beg, const int* __restrict__ deg,
    const int2* __restrict__ csr,
    const float* __restrict__ We, const float* __restrict__ att, const float* __restrict__ bo,
    const float* __restrict__ Wl8, const float* __restrict__ bl8,
    const float* __restrict__ Wr8, const float* __restrict__ br8,
    float* __restrict__ xl8, float* __restrict__ xr8, int n) {
  int lane = threadIdx.x & 63;
  int v = (blockIdx.x * blockDim.x + threadIdx.x) >> 6;
  if (v >= n) return;
  float Wec = We[lane], attc = att[lane], boc = bo[lane];
  float xrc = xr[(size_t)v * CH + lane];
  AggState st = agg_node(xl, csr, row_beg[v], deg[v], Wec, attc, xrc, lane);
  float orow = st.acc / st.s + boc;
  float a = orow * Wl8[lane];
  float b = orow * Wr8[lane];
#pragma unroll
  for (int off = 32; off > 0; off >>= 1) {
    a += __shfl_xor(a, off, 64);
    b += __shfl_xor(b, off, 64);
  }
  if (lane == 0) {
    xl8[v] = a + bl8[0];
    xr8[v] = b + br8[0];
  }
}

// last layer aggregation (scalar channel), lane-per-edge, fused mean pool
__global__ void __launch_bounds__(256) k_agg8_mean(
    const float* __restrict__ xl8, const float* __restrict__ xr8,
    const int* __restrict__ row_beg, const int* __restrict__ deg,
    const int2* __restrict__ csr,
    const float* __restrict__ We, const float* __restrict__ att, const float* __restrict__ bo,
    float* __restrict__ out, int n) {
  int lane = threadIdx.x & 63;
  int wid = threadIdx.x >> 6;
  float We0 = We[0], att0 = att[0], bo0 = bo[0];
  float inv_n = 1.0f / (float)n;
  float local = 0.f;
  int nwaves = gridDim.x * 4;
  for (int v = blockIdx.x * 4 + wid; v < n; v += nwaves) {
    float xrc = xr8[v];
    int beg = row_beg[v], dv = deg[v];
    float m = -INFINITY, s = 0.f, acc = 0.f;
    for (int chunk = 0; chunk < dv; chunk += 64) {
      int idx = chunk + lane;
      bool valid = idx < dv;
      int2 ed = valid ? csr[beg + idx] : make_int2(0, 0);
      float xlc = valid ? xl8[ed.x] : 0.f;
      float ee = fmaf(__int_as_float(ed.y), We0, xlc + xrc);
      float logit = valid ? (ee > 0.f ? ee : 0.2f * ee) * att0 : -INFINITY;
      float bm = logit;
#pragma unroll
      for (int off = 32; off > 0; off >>= 1) bm = fmaxf(bm, __shfl_xor(bm, off, 64));
      float mn = fmaxf(m, bm);
      float p = __expf(logit - mn);
      float pd = p * xlc;
#pragma unroll
      for (int off = 32; off > 0; off >>= 1) {
        p += __shfl_xor(p, off, 64);
        pd += __shfl_xor(pd, off, 64);
      }
      float sc = __expf(m - mn);
      s = fmaf(s, sc, p);
      acc = fmaf(acc, sc, pd);
      m = mn;
    }
    local += (acc / s + bo0) * inv_n;
  }
  __shared__ float sw[4];
  if (lane == 0) sw[wid] = local;
  __syncthreads();
  if (threadIdx.x == 0) atomicAdd(out, sw[0] + sw[1] + sw[2] + sw[3]);
}

// ---- host ---------------------------------------------------------------

extern "C" void kernel_launch(void* const* d_in, const int* in_sizes, int n_in,
                              void* d_out, int out_size, void* d_ws, size_t ws_size,
                              hipStream_t stream) {
  const float* features = (const float*)d_in[0];
  const int* edge_src = (const int*)d_in[1];
  const int* edge_dst = (const int*)d_in[2];
  const float* edge_w = (const float*)d_in[3];
  const int N = in_sizes[0] / CH;
  const int E = in_sizes[1];

  char* p = (char*)d_ws;
  auto take = [&](size_t bytes) {
    char* r = p;
    p += (bytes + 255) & ~(size_t)255;
    return r;
  };
  float* xA = (float*)take((size_t)N * CH * 4);
  float* xB = (float*)take((size_t)N * CH * 4);
  float* xl = (float*)take((size_t)N * CH * 4);
  float* xr = (float*)take((size_t)N * CH * 4);
  int2* csr = (int2*)take((size_t)(E + N) * 8);
  char* zero_region = take((size_t)N * 8 + 256);
  unsigned long long* agg = (unsigned long long*)zero_region;
  int* total = (int*)(zero_region + (size_t)N * 8);
  int* rank = (int*)take((size_t)E * 4);
  float* loop_attr = (float*)take((size_t)N * 4);
  int* deg = (int*)take((size_t)N * 4);
  int* row_beg = (int*)take((size_t)N * 4);
  float* xl8 = (float*)take((size_t)N * 4);
  float* xr8 = (float*)take((size_t)N * 4);

  hipMemsetAsync(zero_region, 0, (size_t)N * 8 + 256, stream);
  hipMemsetAsync(d_out, 0, sizeof(float), stream);

  const int tb = 256;
  k_count<<<(E + tb - 1) / tb, tb, 0, stream>>>(edge_dst, edge_w, E, agg, rank);
  k_alloc<<<(N + tb - 1) / tb, tb, 0, stream>>>(agg, loop_attr, deg, row_beg, total, N);
  k_scatter<<<(E + tb - 1) / tb, tb, 0, stream>>>(edge_src, edge_dst, edge_w, rank, E,
                                                  row_beg, csr);
  k_selfloop<<<(N + tb - 1) / tb, tb, 0, stream>>>(N, row_beg, deg, csr, loop_attr);

  // param pointers
  const float* Wl1 = (const float*)d_in[4];
  const float* bl1 = (const float*)d_in[5];
  const float* Wr1 = (const float*)d_in[6];
  const float* br1 = (const float*)d_in[7];
  const float* We1 = (const float*)d_in[8];
  const float* att1 = (const float*)d_in[9];
  const float* bo1 = (const float*)d_in[10];
  const float* Wlm = (const float*)d_in[11];
  const float* blm = (const float*)d_in[12];
  const float* Wrm = (const float*)d_in[13];
  const float* brm = (const float*)d_in[14];
  const float* Wem = (const float*)d_in[15];
  const float* attm = (const float*)d_in[16];
  const float* bom = (const float*)d_in[17];

  const int agg_grid = ((size_t)N * 64 + tb - 1) / tb;
  const float* x_cur = features;
  float* x_nxt = xA;
  // layers 1..7: transform then aggregate (layer 7 fuses the 64->1 transform)
  for (int layer = 0; layer < 7; ++layer) {
    const float *Wl, *bl, *Wr, *br, *We, *att, *bo;
    if (layer == 0) {
      Wl = Wl1; bl = bl1; Wr = Wr1; br = br1; We = We1; att = att1; bo = bo1;
    } else {
      int i = layer - 1;
      Wl = Wlm + (size_t)i * CH * CH;
      bl = blm + (size_t)i * CH;
      Wr = Wrm + (size_t)i * CH * CH;
      br = brm + (size_t)i * CH;
      We = Wem + (size_t)i * CH;
      att = attm + (size_t)i * CH;
      bo = bom + (size_t)i * CH;
    }
    k_transform<<<1024, 256, 0, stream>>>(x_cur, Wl, bl, Wr, br, xl, xr, N);
    if (layer < 6) {
      k_aggregate<<<agg_grid, tb, 0, stream>>>(xl, xr, row_beg, deg, csr, We, att, bo,
                                               x_nxt, N);
      x_cur = x_nxt;
      x_nxt = (x_nxt == xA) ? xB : xA;
    } else {
      k_aggregate_t8<<<agg_grid, tb, 0, stream>>>(
          xl, xr, row_beg, deg, csr, We, att, bo, (const float*)d_in[18],
          (const float*)d_in[19], (const float*)d_in[20], (const float*)d_in[21], xl8, xr8, N);
    }
  }
  // layer 8 aggregation + mean pool
  k_agg8_mean<<<1024, 256, 0, stream>>>(xl8, xr8, row_beg, deg, csr, (const float*)d_in[22],
                                        (const float*)d_in[23], (const float*)d_in[24],
                                        (float*)d_out, N);
}